// Round 4
// baseline (419.497 us; speedup 1.0000x reference)
//
#include <hip/hip_runtime.h>

// SpikeLoss: loss = 0.5 * sum((outputs - psp(target))^2)
// psp: syn_t = syn_{t-1}*decay + x_t ; psp_t = syn_t/tau, decay = 1 - 1/tau.
//
// R7: abandon global_load_lds. R4/R5b/R6 all cap at ~12 GB/s/CU delivered
// regardless of wave count (6 vs 12) and queue depth (drain vs never-drain):
// signature of a per-CU MLP cap on the LDS-DMA path (consistent w/ m97's
// 54 GB/s/CU L2-resident: fixed ~4.5 KB outstanding, BW ∝ 1/latency).
// Plain register loads (m13: ~25 GB/s/CU from HBM) instead:
//  - coalesced f4 loads into A/B register sets (compiler inserts precise
//    vmcnt waits from dataflow — no manual vmcnt games needed);
//  - target: regs -> ds_write_b128 -> LDS (transpose medium only),
//    2 bufs x 6.4 KB = 12.8 KB -> 12 blocks/CU;
//  - outputs: registers only, never touches LDS; scan writes true syn back
//    in place (R5 consume, verified absmax=0), pass2 reads syn
//    lane-contiguous f4 vs held o-regs;
//  - 64-thread (1-wave) blocks, zero barriers, lgkmcnt fences only;
//  - steady state: tile k+1's 14 loads in flight under tile k's consume.

constexpr int T   = 100;   // trailing axis length
constexpr int PIX = 16;    // pixels per tile
constexpr int TF  = PIX * T;            // 1600 floats = 6.4 KB per array

typedef float f4 __attribute__((ext_vector_type(4)));

__global__ __launch_bounds__(64, 3) void spike_loss_kernel(
    const float* __restrict__ tgt,
    const float* __restrict__ outs,
    const int*   __restrict__ tau_p,
    float*       __restrict__ out,     // [1], pre-zeroed
    int n_tiles, int tiles_per_block)
{
    __shared__ __align__(16) float lds[2][TF];

    const float tau     = (float)tau_p[0];
    const float inv_tau = 1.0f / tau;
    const float decay   = 1.0f - inv_tau;
    float d28 = 1.0f;
    #pragma unroll
    for (int i = 0; i < 28; ++i) d28 *= decay;    // decay^28
    const float d56 = d28 * d28;

    const int tid = threadIdx.x;                  // 0..63, one wave

    const int first = blockIdx.x * tiles_per_block;
    int cnt = n_tiles - first;
    if (cnt < 0) cnt = 0;
    if (cnt > tiles_per_block) cnt = tiles_per_block;
    if (cnt <= 0) return;                         // single wave: safe

    float acc = 0.0f;

    // ---- coalesced register loads: 6 full f4 rounds + 16-lane tail ----
    auto issue = [&](int tile, f4 (&tr)[7], f4 (&orr)[7]) {
        const f4* gt = (const f4*)(tgt  + (size_t)tile * TF);
        const f4* go = (const f4*)(outs + (size_t)tile * TF);
        #pragma unroll
        for (int j = 0; j < 6; ++j) {
            tr[j]  = gt[tid + 64 * j];
            orr[j] = go[tid + 64 * j];
        }
        if (tid < 16) {                 // floats [1536,1600)
            tr[6]  = gt[384 + tid];
            orr[6] = go[384 + tid];
        }
    };

    // ---- regs -> LDS (linear layout), lane-contiguous b128 writes ----
    auto write_lds = [&](int buf, f4 (&tr)[7]) {
        f4* d = (f4*)lds[buf];
        #pragma unroll
        for (int j = 0; j < 6; ++j) d[tid + 64 * j] = tr[j];
        if (tid < 16) d[384 + tid] = tr[6];
    };

    // ---- scan: thread (p=tid>>2, q=tid&3) owns a 28-float segment; true
    //      syn written back in place (b128; 16B-aligned: p*400+q*112) ----
    auto scan = [&](int buf) {
        const int p  = tid >> 2;
        const int q  = tid & 3;
        const int fb = p * T + q * 28;
        f4* tb = (f4*)&lds[buf][fb];
        const int nf4 = (q == 3) ? 4 : 7;     // q==3: floats 84..99

        float s[28];
        float syn = 0.0f;
        #pragma unroll
        for (int j = 0; j < 7; ++j) {
            if (j < nf4) {
                const f4 v = tb[j];
                #pragma unroll
                for (int c = 0; c < 4; ++c) {
                    syn = fmaf(syn, decay, v[c]);
                    s[j * 4 + c] = syn;
                }
            }
        }
        // carry into segment q = true syn at end of segment q-1:
        // S_{q-1} = E_{q-1} + d28*E_{q-2} + d56*E_{q-3}
        const float f1 = __shfl_up(syn, 1, 64);
        const float f2 = __shfl_up(syn, 2, 64);
        const float f3 = __shfl_up(syn, 3, 64);
        float carry = (q >= 1) ? f1 : 0.0f;
        if (q >= 2) carry = fmaf(f2, d28, carry);
        if (q >= 3) carry = fmaf(f3, d56, carry);

        float cp = carry;
        #pragma unroll
        for (int j = 0; j < 7; ++j) {
            if (j < nf4) {
                f4 w;
                #pragma unroll
                for (int c = 0; c < 4; ++c) {
                    cp *= decay;                   // carry*decay^{i+1}
                    w[c] = s[j * 4 + c] + cp;      // true syn
                }
                tb[j] = w;                         // write back in place
            }
        }
    };

    // ---- pass2: lane-contiguous syn from LDS vs held o-regs ----
    auto pass2 = [&](int buf, f4 (&orr)[7]) {
        const f4* p4 = (const f4*)lds[buf];
        #pragma unroll
        for (int j = 0; j < 6; ++j) {
            const f4 sy = p4[tid + 64 * j];
            #pragma unroll
            for (int c = 0; c < 4; ++c) {
                const float d = fmaf(sy[c], -inv_tau, orr[j][c]);
                acc = fmaf(d, d, acc);
            }
        }
        if (tid < 16) {
            const f4 sy = p4[384 + tid];
            #pragma unroll
            for (int c = 0; c < 4; ++c) {
                const float d = fmaf(sy[c], -inv_tau, orr[6][c]);
                acc = fmaf(d, d, acc);
            }
        }
    };

    f4 tA[7], oA[7], tB[7], oB[7];

    // prologue: tile 0 -> A; tile 1 -> B (in flight through tile 0's consume)
    issue(first, tA, oA);
    if (cnt > 1) issue(first + 1, tB, oB);
    write_lds(0, tA);                       // compiler waits tA's vmcnt here
    asm volatile("s_waitcnt lgkmcnt(0)" ::: "memory");

    int k = 0;
    while (true) {
        // even tile: consume buf0/oA; stage tB->buf1; refill A with k+2
        scan(0);
        asm volatile("s_waitcnt lgkmcnt(0)" ::: "memory");
        pass2(0, oA);
        if (k + 1 >= cnt) break;
        write_lds(1, tB);                   // compiler waits tB's vmcnt
        if (k + 2 < cnt) issue(first + k + 2, tA, oA);
        asm volatile("s_waitcnt lgkmcnt(0)" ::: "memory");
        ++k;

        // odd tile: consume buf1/oB; stage tA->buf0; refill B with k+2
        scan(1);
        asm volatile("s_waitcnt lgkmcnt(0)" ::: "memory");
        pass2(1, oB);
        if (k + 1 >= cnt) break;
        write_lds(0, tA);
        if (k + 2 < cnt) issue(first + k + 2, tB, oB);
        asm volatile("s_waitcnt lgkmcnt(0)" ::: "memory");
        ++k;
    }

    // ---- reduction: single wave -> shuffle + one atomic ----
    #pragma unroll
    for (int off = 32; off > 0; off >>= 1)
        acc += __shfl_down(acc, off, 64);
    if (tid == 0)
        atomicAdd(out, 0.5f * acc);
}

extern "C" void kernel_launch(void* const* d_in, const int* in_sizes, int n_in,
                              void* d_out, int out_size, void* d_ws, size_t ws_size,
                              hipStream_t stream) {
    const float* outs = (const float*)d_in[0];   // outputs [B,C,H,W,T]
    const float* tgt  = (const float*)d_in[1];   // target  [B,C,H,W,T]
    const int* tau_p  = (const int*)d_in[3];     // tau_s
    float* out        = (float*)d_out;

    const int n_pixels = in_sizes[0] / T;        // 524288
    const int n_tiles  = n_pixels / PIX;         // 32768

    const int block = 64;                        // 1 wave
    const int grid  = 3072;                      // 12 blocks/CU (LDS: 12.8 KB)
    const int tiles_per_block = (n_tiles + grid - 1) / grid;  // 11

    // d_out is poisoned to 0xAA before every call — zero it (graph-capturable).
    hipMemsetAsync(out, 0, sizeof(float), stream);

    spike_loss_kernel<<<grid, block, 0, stream>>>(
        tgt, outs, tau_p, out, n_tiles, tiles_per_block);
}